// Round 6
// baseline (598.404 us; speedup 1.0000x reference)
//
#include <hip/hip_runtime.h>
#include <math.h>
#include <stdint.h>

typedef float f4u __attribute__((ext_vector_type(4), aligned(4)));
typedef __attribute__((ext_vector_type(8))) short short8;   // 8 bf16 (4 VGPR)
typedef __attribute__((ext_vector_type(4))) float float4v;  // MFMA acc

#define DIM 256
#define KCB 1024
#define PERP_OFF 16777217
#define ENC_OFF  16777218
#define CAP 32
#define EPS 0.008f
#define NPB 128            // n per mega block
#define MEGA_BLOCKS 512    // 512 * 128 = 65536 n

// ---------------------------------------------------------------------------
// numpy pairwise sum-of-squares of a 128-block (8 accumulators, pairwise
// combine); squares rounded separately; no fma contraction.
// ---------------------------------------------------------------------------
__device__ __forceinline__ float np_sumsq128(const float* a, int stride) {
  float r[8];
  #pragma unroll
  for (int j = 0; j < 8; ++j) { float v = a[j * stride]; r[j] = __fmul_rn(v, v); }
  #pragma unroll
  for (int i = 8; i < 128; i += 8) {
    #pragma unroll
    for (int j = 0; j < 8; ++j) {
      float v = a[(i + j) * stride];
      r[j] = __fadd_rn(r[j], __fmul_rn(v, v));
    }
  }
  float s01 = __fadd_rn(r[0], r[1]);
  float s23 = __fadd_rn(r[2], r[3]);
  float s45 = __fadd_rn(r[4], r[5]);
  float s67 = __fadd_rn(r[6], r[7]);
  return __fadd_rn(__fadd_rn(s01, s23), __fadd_rn(s45, s67));
}

__device__ __forceinline__ unsigned short f2bf(float f) {
  unsigned u = __float_as_uint(f);
  u += 0x7FFFu + ((u >> 16) & 1u);     // RNE
  return (unsigned short)(u >> 16);
}

// ---------------------------------------------------------------------------
// k_prep: e_bf16[k][d], np-exact cb_sq[k], zero counts. grid 1024 x 64.
// ---------------------------------------------------------------------------
__global__ __launch_bounds__(64)
void k_prep(const float* __restrict__ cb, unsigned short* __restrict__ e_bf16,
            float* __restrict__ cb_sq, int* __restrict__ counts) {
  const int k = blockIdx.x;
  const int l = threadIdx.x;                  // 0..63
  float4 v = ((const float4*)(cb + k * DIM))[l];
  unsigned short bs[4] = {f2bf(v.x), f2bf(v.y), f2bf(v.z), f2bf(v.w)};
  *(ushort4*)(e_bf16 + k * DIM + l * 4) = *(ushort4*)bs;
  if (l == 0) {
    const float* p = cb + k * DIM;
    cb_sq[k] = __fadd_rn(np_sumsq128(p, 1), np_sumsq128(p + 128, 1));
    counts[k] = 0;
  }
}

// ---------------------------------------------------------------------------
// k_mega: score + filter + insq + refine + epilogue, ONE block per 128-n
// tile (= 2 (b,h) rows; score partition and epi partition align exactly).
//  P0 score: bf16 MFMA approx s = cb_sq[k]-2*dot, online capture vs running
//     cross-lane min (superset; exact set recovered by the end filter).
//     Identical wave mapping / chains to R5's k_score.
//  P1 filter (threads 0..127, in LDS — glist/gcnt never touch HBM) while
//     threads 128..255 concurrently compute np-exact in_sq (same chain as
//     the old k_insq; value partition-independent).
//  P2 refine: 2 threads/n over LDS candidate list; per-candidate fmaf chains
//     bit-identical to R5; lexmin over (dist,idx) is partition/order-free;
//     combine via one shfl_xor. Overflow (cnt>CAP) -> exact full scan.
//  P3/P4 epilogue per half (bh = 2*blk+half), verbatim R5 structure:
//     one-hot enc (nontemporal), xq straight-through + per-bh double loss
//     partial with identical reduction order.
// grid 512 x 256.
// ---------------------------------------------------------------------------
__global__ __launch_bounds__(256, 3)
void k_mega(const float* __restrict__ x, const float* __restrict__ cb,
            const unsigned short* __restrict__ e_bf16,
            const float* __restrict__ cb_sq,
            float* __restrict__ out1, float* __restrict__ enc,
            int* __restrict__ counts, double* __restrict__ partials) {
  __shared__ unsigned int   lcnt[NPB];
  __shared__ unsigned short llist[NPB * CAP];   // 8KB
  __shared__ float          lsc[NPB * CAP];     // 16KB
  __shared__ float          lmin[NPB];
  __shared__ float          isq_s[NPB];
  __shared__ int            idxs[NPB];
  __shared__ double         sm[4];

  const int t    = threadIdx.x;
  const int wv   = t >> 6;
  const int lane = t & 63;
  const int l15  = lane & 15;
  const int quad = lane >> 4;
  const int blk  = blockIdx.x;
  if (t < NPB) lcnt[t] = 0;
  __syncthreads();

  // ---- P0a: B-frag setup: 2 n-groups x 8 K-steps, gathered from fp32 x ----
  short8 Bf[2][8];
  const int nbase = blk * NPB + wv * 32;
  #pragma unroll
  for (int g = 0; g < 2; ++g) {
    const int n = nbase + g * 16 + l15;
    const float* xb = x + (n >> 12) * 1048576 + (n & 4095);
    #pragma unroll
    for (int ks = 0; ks < 8; ++ks) {
      const int d0 = ks * 32 + quad * 8;
      union { unsigned short s[8]; short8 v; } u;
      #pragma unroll
      for (int j = 0; j < 8; ++j) u.s[j] = f2bf(xb[(d0 + j) * 4096]);
      Bf[g][ks] = u.v;
    }
  }

  // ---- P0b: single pass MFMA + online min + online capture ----
  float m[2] = {1e30f, 1e30f};
  for (int ct = 0; ct < 64; ++ct) {
    float4v acc[2];
    #pragma unroll
    for (int g = 0; g < 2; ++g) acc[g] = (float4v){0.f, 0.f, 0.f, 0.f};
    const unsigned short* ap = e_bf16 + (ct * 16 + l15) * DIM + quad * 8;
    #pragma unroll
    for (int ks = 0; ks < 8; ++ks) {
      const short8 a = *(const short8*)(ap + ks * 32);
      #pragma unroll
      for (int g = 0; g < 2; ++g)
        acc[g] = __builtin_amdgcn_mfma_f32_16x16x32_bf16(a, Bf[g][ks], acc[g], 0, 0, 0);
    }
    const float4 cs = *(const float4*)(cb_sq + ct * 16 + quad * 4);
    #pragma unroll
    for (int g = 0; g < 2; ++g) {
      const float sa[4] = {fmaf(-2.f, acc[g].x, cs.x), fmaf(-2.f, acc[g].y, cs.y),
                           fmaf(-2.f, acc[g].z, cs.z), fmaf(-2.f, acc[g].w, cs.w)};
      // running cross-lane min for this n (fmin exact -> order-independent)
      float bm = fminf(fminf(sa[0], sa[1]), fminf(sa[2], sa[3]));
      bm = fminf(bm, m[g]);
      bm = fminf(bm, __shfl_xor(bm, 16));
      bm = fminf(bm, __shfl_xor(bm, 32));
      m[g] = bm;
      const float thr = bm + EPS;
      const float sblk = fminf(fminf(sa[0], sa[1]), fminf(sa[2], sa[3]));
      if (sblk <= thr) {               // rare: skip whole capture block
        const int nl = wv * 32 + g * 16 + l15;
        #pragma unroll
        for (int r = 0; r < 4; ++r) {
          if (sa[r] <= thr) {
            unsigned slot = atomicAdd(&lcnt[nl], 1u);
            if (slot < CAP) {
              llist[nl * CAP + slot] = (unsigned short)(ct * 16 + quad * 4 + r);
              lsc[nl * CAP + slot]   = sa[r];
            }
          }
        }
      }
    }
  }
  if (quad == 0) {
    #pragma unroll
    for (int g = 0; g < 2; ++g) lmin[wv * 32 + g * 16 + l15] = m[g];
  }
  __syncthreads();

  // ---- P1: filter (t<128) || insq (t>=128) ----
  if (t < NPB) {
    const unsigned cnt = lcnt[t];
    unsigned outc = cnt;
    if (cnt <= CAP) {
      const float thrf = lmin[t] + EPS;
      unsigned j = 0;
      for (unsigned i = 0; i < cnt; ++i) {
        const unsigned short c = llist[t * CAP + i];
        if (lsc[t * CAP + i] <= thrf) llist[t * CAP + j++] = c;
      }
      outc = j;
    }
    lcnt[t] = outc;
  } else {
    const int tt = t - NPB;
    const int n  = blk * NPB + tt;
    const float* p = x + (n >> 12) * 1048576 + (n & 4095);
    float h0 = np_sumsq128(p, 4096);
    float h1 = np_sumsq128(p + 128 * 4096, 4096);
    isq_s[tt] = __fadd_rn(h0, h1);
  }
  __syncthreads();

  // ---- P2: refine, 2 threads per n ----
  {
    const int nl = t >> 1;            // 0..127
    const int q  = t & 1;
    const int n  = blk * NPB + nl;
    const unsigned cnt = lcnt[nl];
    const float* xb = x + (n >> 12) * 1048576 + (n & 4095);
    const float isq = isq_s[nl];
    float bv = 1e30f; int bc = 0x7FFFFFFF;

    if (cnt <= CAP) {
      const unsigned short* lst = llist + nl * CAP;
      for (unsigned i = q; i < cnt; i += 2) {
        const int c1 = lst[i];
        const float4* e1 = (const float4*)(cb + c1 * DIM);
        float d1 = 0.f;
        #pragma unroll 4
        for (int qq = 0; qq < 64; ++qq) {
          const float4 a = e1[qq];
          d1 = fmaf(xb[(qq * 4 + 0) * 4096], a.x, d1);
          d1 = fmaf(xb[(qq * 4 + 1) * 4096], a.y, d1);
          d1 = fmaf(xb[(qq * 4 + 2) * 4096], a.z, d1);
          d1 = fmaf(xb[(qq * 4 + 3) * 4096], a.w, d1);
        }
        const float dist = __fsub_rn(__fadd_rn(isq, cb_sq[c1]), __fmul_rn(2.f, d1));
        if (dist < bv || (dist == bv && c1 < bc)) { bv = dist; bc = c1; }
      }
    } else {
      // overflow fallback (P ~ 1e-9): exact full scan
      for (int c = q; c < KCB; c += 2) {
        const float4* e1 = (const float4*)(cb + c * DIM);
        float d1 = 0.f;
        #pragma unroll 4
        for (int qq = 0; qq < 64; ++qq) {
          const float4 a = e1[qq];
          d1 = fmaf(xb[(qq * 4 + 0) * 4096], a.x, d1);
          d1 = fmaf(xb[(qq * 4 + 1) * 4096], a.y, d1);
          d1 = fmaf(xb[(qq * 4 + 2) * 4096], a.z, d1);
          d1 = fmaf(xb[(qq * 4 + 3) * 4096], a.w, d1);
        }
        const float dist = __fsub_rn(__fadd_rn(isq, cb_sq[c]), __fmul_rn(2.f, d1));
        if (dist < bv || (dist == bv && c < bc)) { bv = dist; bc = c; }
      }
    }
    // combine 2 lanes (lexmin -> order independent)
    {
      const float ov = __shfl_xor(bv, 1); const int oc = __shfl_xor(bc, 1);
      if (ov < bv || (ov == bv && oc < bc)) { bv = ov; bc = oc; }
    }
    if (q == 0) { idxs[nl] = bc; atomicAdd(counts + bc, 1); }
  }
  __syncthreads();

  // ---- P3/P4: epilogue, one (b,h) sub-tile per half ----
  const int w4 = (t & 15) * 4;
  const int cg = t >> 4;
  #pragma unroll
  for (int half = 0; half < 2; ++half) {
    const int bh = blk * 2 + half;
    const int b  = bh >> 6, h = bh & 63;
    const int* idx_h = idxs + half * 64;

    // one-hot encodings (coalesced, nontemporal)
    {
      float* base = enc + (size_t)bh * 65536 + t * 4;
      #pragma unroll 8
      for (int r = 0; r < 64; ++r) {
        const int bi = idx_h[r];
        f4u v = {0.f, 0.f, 0.f, 0.f};
        if ((bi >> 2) == t) {
          if ((bi & 3) == 0) v.x = 1.f; else if ((bi & 3) == 1) v.y = 1.f;
          else if ((bi & 3) == 2) v.z = 1.f; else v.w = 1.f;
        }
        __builtin_nontemporal_store(v, (f4u*)(base + r * 1024));
      }
    }

    // xq straight-through + double loss partial (verbatim R5 per-bh order)
    float qf[4][16];
    #pragma unroll
    for (int i = 0; i < 4; ++i) {
      const float4* rp = (const float4*)(cb + idx_h[w4 + i] * DIM + cg * 16);
      #pragma unroll
      for (int jq = 0; jq < 4; ++jq) {
        const float4 v = rp[jq];
        qf[i][jq * 4 + 0] = v.x; qf[i][jq * 4 + 1] = v.y;
        qf[i][jq * 4 + 2] = v.z; qf[i][jq * 4 + 3] = v.w;
      }
    }

    double s = 0.0;
    #pragma unroll
    for (int j = 0; j < 16; ++j) {
      const int c = cg * 16 + j;
      const size_t off = ((size_t)b << 20) + ((size_t)c << 12) + (h << 6) + w4;
      const float4 xp = *(const float4*)(x + off);
      const float q0 = qf[0][j], q1 = qf[1][j], q2 = qf[2][j], q3 = qf[3][j];
      const float d0 = __fsub_rn(q0, xp.x), d1 = __fsub_rn(q1, xp.y);
      const float d2 = __fsub_rn(q2, xp.z), d3 = __fsub_rn(q3, xp.w);
      f4u o;
      o.x = __fadd_rn(xp.x, d0); o.y = __fadd_rn(xp.y, d1);
      o.z = __fadd_rn(xp.z, d2); o.w = __fadd_rn(xp.w, d3);
      __builtin_nontemporal_store(o, (f4u*)(out1 + off));
      s += (double)(d0*d0) + (double)(d1*d1) + (double)(d2*d2) + (double)(d3*d3);
    }
    #pragma unroll
    for (int off = 32; off > 0; off >>= 1) s += __shfl_down(s, off);
    if ((t & 63) == 0) sm[t >> 6] = s;
    __syncthreads();
    if (t == 0) partials[bh] = (sm[0] + sm[1]) + (sm[2] + sm[3]);
    __syncthreads();   // protect sm before next half
  }
}

// ---------------------------------------------------------------------------
// k_final: loss + perplexity. grid 1 x 256
// ---------------------------------------------------------------------------
__global__ __launch_bounds__(256)
void k_final(const double* __restrict__ partials, const int* __restrict__ counts,
             float* __restrict__ out) {
  const int t = threadIdx.x;
  double s = 0.0;
  #pragma unroll
  for (int i = 0; i < 4; ++i) s += partials[t + i * 256];
  #pragma unroll
  for (int off = 32; off > 0; off >>= 1) s += __shfl_down(s, off);
  __shared__ double sm[4];
  __shared__ float smf[4];
  if ((t & 63) == 0) sm[t >> 6] = s;

  float ps = 0.f;
  #pragma unroll
  for (int i = 0; i < 4; ++i) {
    const float p = (float)counts[t + i * 256] * (1.0f / 65536.0f);
    ps += p * logf(1.0e10f + p);
  }
  #pragma unroll
  for (int off = 32; off > 0; off >>= 1) ps += __shfl_down(ps, off);
  if ((t & 63) == 0) smf[t >> 6] = ps;
  __syncthreads();
  if (t == 0) {
    const double tot = (sm[0] + sm[1]) + (sm[2] + sm[3]);
    const float mval = (float)(tot / 16777216.0);
    out[0] = mval + 0.25f * mval;
    out[PERP_OFF] = expf(-((smf[0] + smf[1]) + (smf[2] + smf[3])));
  }
}

// ---------------------------------------------------------------------------
extern "C" void kernel_launch(void* const* d_in, const int* in_sizes, int n_in,
                              void* d_out, int out_size, void* d_ws, size_t ws_size,
                              hipStream_t stream) {
  const float* x  = (const float*)d_in[0];   // (16,256,64,64) fp32
  const float* cb = (const float*)d_in[1];   // (1024,256) fp32
  float* out = (float*)d_out;
  char*  ws  = (char*)d_ws;

  int*            counts   = (int*)(ws + 0);                //   4 KB
  float*          cb_sq    = (float*)(ws + 4096);           //   4 KB
  double*         partials = (double*)(ws + 8192);          //   8 KB
  unsigned short* e_bf16   = (unsigned short*)(ws + 16384); // 512 KB

  k_prep <<<1024, 64, 0, stream>>>(cb, e_bf16, cb_sq, counts);
  k_mega <<<MEGA_BLOCKS, 256, 0, stream>>>(x, cb, e_bf16, cb_sq, out + 1,
                                           out + ENC_OFF, counts, partials);
  k_final<<<1, 256, 0, stream>>>(partials, counts, out);
}